// Round 10
// baseline (130.543 us; speedup 1.0000x reference)
//
#include <hip/hip_runtime.h>

#define THREADS 512
#define NBLK 1024    // 65536 rows / 64 per block
#define BUFSZ 40960  // per buffer: A fp32 8KB + B f16 32KB
#define BOFF 8192

typedef _Float16 half8 __attribute__((ext_vector_type(8)));
typedef float floatx4 __attribute__((ext_vector_type(4)));

// --- Kernel 1: W [512(k)][512(n)] fp32 -> Wt [512(n)][512(k)] f16 ---
__global__ void wcvt_kernel(const float* __restrict__ W, unsigned short* __restrict__ Wt) {
  __shared__ float tile[32][33];
  const int tx = threadIdx.x, ty = threadIdx.y;
  const int nb = blockIdx.x * 32, kb = blockIdx.y * 32;
#pragma unroll
  for (int i = 0; i < 4; ++i)
    tile[ty + 8 * i][tx] = W[(size_t)(kb + ty + 8 * i) * 512 + nb + tx];
  __syncthreads();
#pragma unroll
  for (int i = 0; i < 4; ++i) {
    union { _Float16 h; unsigned short u; } v;
    v.h = (_Float16)tile[tx][ty + 8 * i];
    Wt[(size_t)(nb + ty + 8 * i) * 512 + kb + tx] = v.u;
  }
}

// --- Kernel 2: fused GEMM + surrogate-sigmoid + rowwise LayerNorm ---
// FRAGMENT-LINEAR LDS (fixes the 8-way bank conflict present in r1-r9):
// each MFMA fragment is a contiguous 1KB region, lane L at byte L*16 ->
// ds_read_b128 is perfectly lane-linear (zero conflicts). global_load_lds
// writes linearly; the data permutation lives in the per-lane GLOBAL source
// address (thread (wave,l15,g) fetches exactly the element for its slot).
// Geometry: block 64x512, 8 waves (2 wrow x 4 wcol), wave tile 32x128,
// acc[2][8]=64 AGPR, 80KB LDS -> 2 blocks/CU, 4 waves/SIMD.
// BK=32, 16 tiles, double buffer, counted vmcnt(5) (stage(c+1) always in
// flight). Per tile: vmcnt -> bar -> 12 ds_read + cvt -> lgkm0 -> bar ->
// stage(c+2) -> 16 MFMA. Refill is issued only after the all-waves-read
// barrier (race-free; r3 lesson).
// LDS buffer: A [0,8K): region rho=wave (1KB): A-frag (wrow=rho>>2,
//   m=(rho>>1)&1, half=rho&1), fp32. B [8K,40K): region rho=wave*4+i:
//   B-frag (wcol=rho>>3, n=rho&7), f16.
__global__ __launch_bounds__(THREADS, 4) void lif_fused_kernel(
    const float* __restrict__ A, const unsigned short* __restrict__ Wt,
    const float* __restrict__ bias, const float* __restrict__ lnw,
    const float* __restrict__ lnb, float* __restrict__ out) {
  __shared__ uint4 smem4[5120];  // 81920 bytes
  unsigned char* smem = (unsigned char*)smem4;

  const int tid  = threadIdx.x;
  const int lane = tid & 63;
  const int wave = tid >> 6;   // 0..7
  const int wrow = wave >> 2;  // 0..1
  const int wcol = wave & 3;   // 0..3
  const int l15  = lane & 15;
  const int g    = lane >> 4;  // 0..3
  const int rowBase = blockIdx.x * 64;

  // --- staging sources (per-lane global address = fragment element) ---
  // A region rho = wave: row = (rho>>2)*32 + ((rho>>1)&1)*16 + l15,
  //   k-offset = g*8 + (rho&1)*4  (fp32, 16B).
  const int aRowS = (wave >> 2) * 32 + ((wave >> 1) & 1) * 16 + l15;
  const float* asrc = A + (size_t)(rowBase + aRowS) * 512 + g * 8 + (wave & 1) * 4;
  // B region rho = wave*4+i: col = (wave>>1)*128 + (wave&1)*64 + i*16 + l15,
  //   k-offset = g*8  (f16, 16B). i enters as +i*16 rows.
  const unsigned short* bsrc0 =
      Wt + (size_t)((wave >> 1) * 128 + (wave & 1) * 64 + l15) * 512 + g * 8;

  auto stage = [&](int buf, int c) {
    int oA = buf * BUFSZ + wave * 1024;
    oA = __builtin_amdgcn_readfirstlane(oA);
    __builtin_amdgcn_global_load_lds(
        (const __attribute__((address_space(1))) void*)(asrc + c * 32),
        (__attribute__((address_space(3))) void*)(smem + oA), 16, 0, 0);
#pragma unroll
    for (int i = 0; i < 4; ++i) {
      int oB = buf * BUFSZ + BOFF + (wave * 4 + i) * 1024;
      oB = __builtin_amdgcn_readfirstlane(oB);
      __builtin_amdgcn_global_load_lds(
          (const __attribute__((address_space(1))) void*)(bsrc0 + (size_t)i * 16 * 512 + c * 32),
          (__attribute__((address_space(3))) void*)(smem + oB), 16, 0, 0);
    }
  };

  // --- fragment read bases (lane-linear, zero-conflict) ---
  const int aRd = wrow * 4096 + lane * 16;         // + m*2048 + h*1024 + buf*BUFSZ
  const int bRd = BOFF + wcol * 8192 + lane * 16;  // + n*1024 + buf*BUFSZ

  floatx4 acc[2][8];
#pragma unroll
  for (int m = 0; m < 2; ++m)
#pragma unroll
    for (int n = 0; n < 8; ++n)
      acc[m][n] = (floatx4){0.f, 0.f, 0.f, 0.f};

  auto mk = [](float4 lo, float4 hi) {
    half8 t;
    t[0] = (_Float16)lo.x; t[1] = (_Float16)lo.y;
    t[2] = (_Float16)lo.z; t[3] = (_Float16)lo.w;
    t[4] = (_Float16)hi.x; t[5] = (_Float16)hi.y;
    t[6] = (_Float16)hi.z; t[7] = (_Float16)hi.w;
    return t;
  };

  // Prologue: tiles 0 and 1 in flight (5 DMA each).
  stage(0, 0);
  stage(1, 1);

#pragma unroll
  for (int c = 0; c < 16; ++c) {
    if (c < 15) {
      asm volatile("s_waitcnt vmcnt(5)" ::: "memory");  // stage(c) landed
    } else {
      asm volatile("s_waitcnt vmcnt(0)" ::: "memory");
    }
    __builtin_amdgcn_s_barrier();
    __builtin_amdgcn_sched_barrier(0);

    const unsigned char* base = smem + (c & 1) * BUFSZ;
    // A fragments (fp32 -> f16 in-register), conflict-free lane-linear reads.
    half8 a0 = mk(*(const float4*)(base + aRd),
                  *(const float4*)(base + aRd + 1024));
    half8 a1 = mk(*(const float4*)(base + aRd + 2048),
                  *(const float4*)(base + aRd + 3072));
    // B fragments.
    half8 b0 = *(const half8*)(base + bRd);
    half8 b1 = *(const half8*)(base + bRd + 1024);
    half8 b2 = *(const half8*)(base + bRd + 2048);
    half8 b3 = *(const half8*)(base + bRd + 3072);
    half8 b4 = *(const half8*)(base + bRd + 4096);
    half8 b5 = *(const half8*)(base + bRd + 5120);
    half8 b6 = *(const half8*)(base + bRd + 6144);
    half8 b7 = *(const half8*)(base + bRd + 7168);
    asm volatile("s_waitcnt lgkmcnt(0)" ::: "memory");
    __builtin_amdgcn_sched_barrier(0);
    __builtin_amdgcn_s_barrier();  // all waves' reads done -> refill safe
    __builtin_amdgcn_sched_barrier(0);
    if (c < 14) stage(c & 1, c + 2);

    __builtin_amdgcn_s_setprio(1);
    acc[0][0] = __builtin_amdgcn_mfma_f32_16x16x32_f16(a0, b0, acc[0][0], 0, 0, 0);
    acc[1][0] = __builtin_amdgcn_mfma_f32_16x16x32_f16(a1, b0, acc[1][0], 0, 0, 0);
    acc[0][1] = __builtin_amdgcn_mfma_f32_16x16x32_f16(a0, b1, acc[0][1], 0, 0, 0);
    acc[1][1] = __builtin_amdgcn_mfma_f32_16x16x32_f16(a1, b1, acc[1][1], 0, 0, 0);
    acc[0][2] = __builtin_amdgcn_mfma_f32_16x16x32_f16(a0, b2, acc[0][2], 0, 0, 0);
    acc[1][2] = __builtin_amdgcn_mfma_f32_16x16x32_f16(a1, b2, acc[1][2], 0, 0, 0);
    acc[0][3] = __builtin_amdgcn_mfma_f32_16x16x32_f16(a0, b3, acc[0][3], 0, 0, 0);
    acc[1][3] = __builtin_amdgcn_mfma_f32_16x16x32_f16(a1, b3, acc[1][3], 0, 0, 0);
    acc[0][4] = __builtin_amdgcn_mfma_f32_16x16x32_f16(a0, b4, acc[0][4], 0, 0, 0);
    acc[1][4] = __builtin_amdgcn_mfma_f32_16x16x32_f16(a1, b4, acc[1][4], 0, 0, 0);
    acc[0][5] = __builtin_amdgcn_mfma_f32_16x16x32_f16(a0, b5, acc[0][5], 0, 0, 0);
    acc[1][5] = __builtin_amdgcn_mfma_f32_16x16x32_f16(a1, b5, acc[1][5], 0, 0, 0);
    acc[0][6] = __builtin_amdgcn_mfma_f32_16x16x32_f16(a0, b6, acc[0][6], 0, 0, 0);
    acc[1][6] = __builtin_amdgcn_mfma_f32_16x16x32_f16(a1, b6, acc[1][6], 0, 0, 0);
    acc[0][7] = __builtin_amdgcn_mfma_f32_16x16x32_f16(a0, b7, acc[0][7], 0, 0, 0);
    acc[1][7] = __builtin_amdgcn_mfma_f32_16x16x32_f16(a1, b7, acc[1][7], 0, 0, 0);
    __builtin_amdgcn_s_setprio(0);
    __builtin_amdgcn_sched_barrier(0);
  }
  __syncthreads();

  // --- Epilogue: bias + surrogate spike + fused LayerNorm ---
  float bcol[8], lsc[8], lbc[8];
#pragma unroll
  for (int n = 0; n < 8; ++n) {
    const int col = wcol * 128 + n * 16 + l15;
    bcol[n] = bias[col];
    lsc[n]  = lnw[col];
    lbc[n]  = lnb[col];
  }
#pragma unroll
  for (int m = 0; m < 2; ++m)
#pragma unroll
    for (int n = 0; n < 8; ++n)
#pragma unroll
      for (int r = 0; r < 4; ++r) {
        // alpha=exp(-50): v == current in fp32; spike = fast_sigmoid(v-0.5, 4)
        float x  = acc[m][n][r] + bcol[n] - 0.5f;
        float bx = 4.0f * x;
        acc[m][n][r] = 0.5f * bx / (1.0f + fabsf(bx)) + 0.5f;
      }

  float rs[2][4], rq[2][4];
#pragma unroll
  for (int m = 0; m < 2; ++m)
#pragma unroll
    for (int r = 0; r < 4; ++r) {
      float s = 0.f, q = 0.f;
#pragma unroll
      for (int n = 0; n < 8; ++n) {
        float v = acc[m][n][r];
        s += v;
        q += v * v;
      }
      rs[m][r] = s;
      rq[m][r] = q;
    }
#pragma unroll
  for (int d = 1; d < 16; d <<= 1) {
#pragma unroll
    for (int m = 0; m < 2; ++m)
#pragma unroll
      for (int r = 0; r < 4; ++r) {
        rs[m][r] += __shfl_xor(rs[m][r], d, 16);
        rq[m][r] += __shfl_xor(rq[m][r], d, 16);
      }
  }

  float* redS = (float*)smem4;   // [64][4]
  float* redQ = redS + 256;      // [64][4]
  float* mv   = redQ + 256;      // [64][2]
  if (l15 == 0) {
#pragma unroll
    for (int m = 0; m < 2; ++m)
#pragma unroll
      for (int r = 0; r < 4; ++r) {
        const int row = wrow * 32 + m * 16 + g * 4 + r;
        redS[row * 4 + wcol] = rs[m][r];
        redQ[row * 4 + wcol] = rq[m][r];
      }
  }
  __syncthreads();
  if (tid < 64) {
    const float S = redS[tid * 4] + redS[tid * 4 + 1] + redS[tid * 4 + 2] + redS[tid * 4 + 3];
    const float Q = redQ[tid * 4] + redQ[tid * 4 + 1] + redQ[tid * 4 + 2] + redQ[tid * 4 + 3];
    const float mean = S * (1.0f / 512.0f);
    const float var  = Q * (1.0f / 512.0f) - mean * mean;
    mv[tid * 2]     = mean;
    mv[tid * 2 + 1] = rsqrtf(var + 1e-6f);
  }
  __syncthreads();

#pragma unroll
  for (int m = 0; m < 2; ++m)
#pragma unroll
    for (int r = 0; r < 4; ++r) {
      const int row  = wrow * 32 + m * 16 + g * 4 + r;
      const float mean = mv[row * 2];
      const float rstd = mv[row * 2 + 1];
      const size_t base = (size_t)(rowBase + row) * 512;
#pragma unroll
      for (int n = 0; n < 8; ++n) {
        const int col = wcol * 128 + n * 16 + l15;
        out[base + col] = (acc[m][n][r] - mean) * rstd * lsc[n] + lbc[n];
      }
    }
}

extern "C" void kernel_launch(void* const* d_in, const int* in_sizes, int n_in,
                              void* d_out, int out_size, void* d_ws, size_t ws_size,
                              hipStream_t stream) {
  const float* spikes = (const float*)d_in[0];
  const float* W      = (const float*)d_in[1];
  const float* b      = (const float*)d_in[2];
  const float* lnw    = (const float*)d_in[3];
  const float* lnb    = (const float*)d_in[4];
  float* out = (float*)d_out;
  unsigned short* Wt = (unsigned short*)d_ws;  // 512*512*2 = 512 KB scratch

  wcvt_kernel<<<dim3(16, 16), dim3(32, 8), 0, stream>>>(W, Wt);
  lif_fused_kernel<<<NBLK, THREADS, 0, stream>>>(spikes, Wt, b, lnw, lnb, out);
}